// Round 3
// baseline (16367.084 us; speedup 1.0000x reference)
//
#include <hip/hip_runtime.h>
#include <hip/hip_bf16.h>
#include <hip/hip_cooperative_groups.h>

namespace cg = cooperative_groups;

#define N_CHAR 128
#define EMBED  256
#define HIDDEN 1024
#define BATCH  64
#define SEQ    512

__device__ __forceinline__ float dot4(const float4 a, const float4 b) {
  return a.x * b.x + a.y * b.y + a.z * b.z + a.w * b.w;
}

// ---------------------------------------------------------------------------
// P[c][j] = sum_k embeddings[c][k] * W_ih[j][k]   (128 x 1024)
// ---------------------------------------------------------------------------
__global__ void pk(const float* __restrict__ emb, const float* __restrict__ Wih,
                   float* __restrict__ P) {
  __shared__ float e[EMBED];
  const int c = blockIdx.x >> 2;
  const int j = ((blockIdx.x & 3) << 8) + threadIdx.x;
  if (threadIdx.x < EMBED / 4) {
    reinterpret_cast<float4*>(e)[threadIdx.x] =
        reinterpret_cast<const float4*>(emb + c * EMBED)[threadIdx.x];
  }
  __syncthreads();
  const float4* w = reinterpret_cast<const float4*>(Wih + j * EMBED);
  float acc = 0.f;
#pragma unroll 8
  for (int k4 = 0; k4 < EMBED / 4; ++k4)
    acc += dot4(w[k4], reinterpret_cast<const float4*>(e)[k4]);
  P[c * HIDDEN + j] = acc;
}

// ---------------------------------------------------------------------------
// Persistent cooperative RNN kernel.
// Grid 256 = 8 b-tiles(8) x 32 j-tiles(32); block 256 threads (4 waves).
// Thread (jg = tid>>6, ks = tid&63):
//   W_hh fragment [8 j rows][16 k] = 128 VGPRs, loaded ONCE for all 512 steps.
//   Per step: 8 bl x 2 jq float4 accumulators, h float4 reused for 8 j rows.
// Reduction over ks via LDS partials; finish distributed over all 4 waves.
// ---------------------------------------------------------------------------
__global__ void __launch_bounds__(256, 1) persist(
    float* __restrict__ ha, float* __restrict__ hb,
    const float* __restrict__ Whh, const float* __restrict__ P,
    const int* __restrict__ t, const float* __restrict__ h0v) {
  __shared__ float4 part[64 * 64];   // [task(bl*8+gq)][ks]  64 KB
  __shared__ int    t_lds[8][SEQ];   // block's batch rows of t  16 KB
  __shared__ float4 P_lds[1024];     // [c][gq] j-slice of P     16 KB

  cg::grid_group grid = cg::this_grid();

  const int tid = threadIdx.x;
  const int jg = tid >> 6;   // wave id: j rows j0 + jg*8 .. +7
  const int ks = tid & 63;   // lane id: k = ks*4 + q*256 + r
  const int b0 = (blockIdx.x >> 5) * 8;    // 8 batches
  const int j0 = (blockIdx.x & 31) * 32;   // 32 hidden rows

  // --- W_hh fragment into registers (32 float4 = 128 VGPR), once ---
  float4 w[2][4][4];  // [jql][jj][q]
#pragma unroll
  for (int jql = 0; jql < 2; ++jql) {
#pragma unroll
    for (int jj = 0; jj < 4; ++jj) {
      const float4* wr = reinterpret_cast<const float4*>(
          Whh + (j0 + jg * 8 + jql * 4 + jj) * HIDDEN + (ks << 2));
      w[jql][jj][0] = wr[0];
      w[jql][jj][1] = wr[64];
      w[jql][jj][2] = wr[128];
      w[jql][jj][3] = wr[192];
    }
  }

  // --- preload t slice (1024 int4) and P slice (1024 float4) ---
#pragma unroll
  for (int i = 0; i < 4; ++i) {
    const int i4 = tid + 256 * i;
    const int row = i4 >> 7;          // 128 int4 per row
    const int col = (i4 & 127) * 4;
    *reinterpret_cast<int4*>(&t_lds[row][col]) =
        *reinterpret_cast<const int4*>(t + (b0 + row) * SEQ + col);
  }
#pragma unroll
  for (int i = 0; i < 4; ++i) {
    const int idx = tid + 256 * i;
    const int c = idx >> 3;
    const int gq = idx & 7;
    P_lds[idx] = *reinterpret_cast<const float4*>(P + c * HIDDEN + j0 + gq * 4);
  }

  // --- init h = broadcast h0 (each block writes its own tile) ---
  {
    const int b = b0 + (tid >> 5);
    const int j = j0 + (tid & 31);
    ha[b * HIDDEN + j] = h0v[j];
  }
  grid.sync();

  float* cur = ha;
  float* nxt = hb;

  for (int s = 0; s < SEQ; ++s) {
    // --- compute: 8 bl x 8 j x 16 k = 1024 FMA per thread ---
    float4 acc[8][2];
#pragma unroll
    for (int bl = 0; bl < 8; ++bl) {
      const float4* hp =
          reinterpret_cast<const float4*>(cur + (b0 + bl) * HIDDEN + (ks << 2));
      float4 hq[4];
      hq[0] = hp[0];
      hq[1] = hp[64];
      hq[2] = hp[128];
      hq[3] = hp[192];
#pragma unroll
      for (int jql = 0; jql < 2; ++jql) {
        float4 a = make_float4(0.f, 0.f, 0.f, 0.f);
#pragma unroll
        for (int q = 0; q < 4; ++q) {
          a.x += dot4(w[jql][0][q], hq[q]);
          a.y += dot4(w[jql][1][q], hq[q]);
          a.z += dot4(w[jql][2][q], hq[q]);
          a.w += dot4(w[jql][3][q], hq[q]);
        }
        acc[bl][jql] = a;
      }
    }

    // --- write partials: [bl*8 + jg*2 + jql][ks], lanes consecutive ---
#pragma unroll
    for (int bl = 0; bl < 8; ++bl) {
#pragma unroll
      for (int jql = 0; jql < 2; ++jql)
        part[(bl * 8 + jg * 2 + jql) * 64 + ks] = acc[bl][jql];
    }
    __syncthreads();

    // --- finish: 64 tasks x 4 lanes; each lane sums 16 partials ---
    {
      const int t4 = tid >> 2;  // task: bl = t4>>3, gq = t4&7
      const int q = tid & 3;
      const float4* p = &part[t4 * 64 + q * 16];
      float4 ssum = make_float4(0.f, 0.f, 0.f, 0.f);
#pragma unroll
      for (int i = 0; i < 16; ++i) {
        const float4 v = p[(i + tid) & 15];  // lane-rotated: even banks
        ssum.x += v.x; ssum.y += v.y; ssum.z += v.z; ssum.w += v.w;
      }
      // reduce across the 4 lanes of the task
      ssum.x += __shfl_xor(ssum.x, 1); ssum.y += __shfl_xor(ssum.y, 1);
      ssum.z += __shfl_xor(ssum.z, 1); ssum.w += __shfl_xor(ssum.w, 1);
      ssum.x += __shfl_xor(ssum.x, 2); ssum.y += __shfl_xor(ssum.y, 2);
      ssum.z += __shfl_xor(ssum.z, 2); ssum.w += __shfl_xor(ssum.w, 2);
      if (q == 0) {
        const int bl = t4 >> 3;
        const int gq = t4 & 7;
        const int c = t_lds[bl][s];
        const float4 pq = P_lds[c * 8 + gq];
        float4 ho;
        ho.x = tanhf(pq.x + ssum.x);
        ho.y = tanhf(pq.y + ssum.y);
        ho.z = tanhf(pq.z + ssum.z);
        ho.w = tanhf(pq.w + ssum.w);
        *reinterpret_cast<float4*>(nxt + (b0 + bl) * HIDDEN + j0 + gq * 4) = ho;
      }
    }
    grid.sync();
    float* tmp = cur; cur = nxt; nxt = tmp;
  }
}

// ---------------------------------------------------------------------------
// out[b][c] = sum_k h[b][k] * W_proj[c][k] + b_proj[c]
// ---------------------------------------------------------------------------
__global__ void outk(const float* __restrict__ h, const float* __restrict__ Wp,
                     const float* __restrict__ bp, float* __restrict__ out) {
  __shared__ float hbuf[HIDDEN];
  const int b = blockIdx.x;
  const int c = threadIdx.x;
  for (int i = threadIdx.x; i < HIDDEN / 4; i += blockDim.x) {
    reinterpret_cast<float4*>(hbuf)[i] =
        reinterpret_cast<const float4*>(h + b * HIDDEN)[i];
  }
  __syncthreads();
  const float4* w = reinterpret_cast<const float4*>(Wp + c * HIDDEN);
  float acc = 0.f;
#pragma unroll 8
  for (int k4 = 0; k4 < HIDDEN / 4; ++k4)
    acc += dot4(w[k4], reinterpret_cast<const float4*>(hbuf)[k4]);
  out[b * N_CHAR + c] = acc + bp[c];
}

// ---------------------------------------------------------------------------
extern "C" void kernel_launch(void* const* d_in, const int* in_sizes, int n_in,
                              void* d_out, int out_size, void* d_ws, size_t ws_size,
                              hipStream_t stream) {
  const int*   t   = (const int*)d_in[0];
  const float* emb = (const float*)d_in[1];
  const float* Wih = (const float*)d_in[2];
  const float* Whh = (const float*)d_in[3];
  const float* h0v = (const float*)d_in[4];
  const float* Wp  = (const float*)d_in[5];
  const float* bp  = (const float*)d_in[6];
  float* out = (float*)d_out;

  float* P  = (float*)d_ws;                 // 128*1024
  float* ha = P + N_CHAR * HIDDEN;          // 64*1024
  float* hb = ha + BATCH * HIDDEN;          // 64*1024

  pk<<<512, 256, 0, stream>>>(emb, Wih, P);

  {
    float* a0 = ha; float* a1 = hb;
    const float* a2 = Whh; const float* a3 = P;
    const int* a4 = t; const float* a5 = h0v;
    void* kargs[] = {&a0, &a1, &a2, &a3, &a4, &a5};
    hipLaunchCooperativeKernel((const void*)persist, dim3(256), dim3(256),
                               kargs, 0, stream);
  }

  // SEQ even -> final state in ha
  outk<<<BATCH, 128, 0, stream>>>(ha, Wp, bp, out);
}

// Round 5
// 5289.466 us; speedup vs baseline: 3.0943x; 3.0943x over previous
//
#include <hip/hip_runtime.h>
#include <hip/hip_bf16.h>

#define N_CHAR 128
#define EMBED  256
#define HIDDEN 1024
#define BATCH  64
#define SEQ    512

#define GBLK 32  // blocks per group
#define GB   8   // batch rows per group

__device__ __forceinline__ float dot4(const float4 a, const float4 b) {
  return a.x * b.x + a.y * b.y + a.z * b.z + a.w * b.w;
}

// ---------------------------------------------------------------------------
// P[c][j] = sum_k embeddings[c][k] * W_ih[j][k]   (128 x 1024)
// ---------------------------------------------------------------------------
__global__ void pk(const float* __restrict__ emb, const float* __restrict__ Wih,
                   float* __restrict__ P) {
  __shared__ float e[EMBED];
  const int c = blockIdx.x >> 2;
  const int j = ((blockIdx.x & 3) << 8) + threadIdx.x;
  if (threadIdx.x < EMBED / 4) {
    reinterpret_cast<float4*>(e)[threadIdx.x] =
        reinterpret_cast<const float4*>(emb + c * EMBED)[threadIdx.x];
  }
  __syncthreads();
  const float4* w = reinterpret_cast<const float4*>(Wih + j * EMBED);
  float acc = 0.f;
#pragma unroll 8
  for (int k4 = 0; k4 < EMBED / 4; ++k4)
    acc += dot4(w[k4], reinterpret_cast<const float4*>(e)[k4]);
  P[c * HIDDEN + j] = acc;
}

// ---------------------------------------------------------------------------
// h[b][j] = h0[j];  zero the 256 progress flags
// ---------------------------------------------------------------------------
__global__ void initk(const float* __restrict__ h0v, float* __restrict__ h,
                      int* __restrict__ flags) {
  const int i = blockIdx.x * blockDim.x + threadIdx.x;
  h[i] = h0v[i & (HIDDEN - 1)];
  if (i < 256) flags[i] = 0;
}

// ---------------------------------------------------------------------------
// Persistent RNN, group-local flag sync (no grid-wide barrier).
// 256 blocks = 8 groups x 32 members; block = 256 threads (4 waves).
//   group g owns batch rows [8g, 8g+8); member m owns W_hh rows [32m, 32m+32)
//   in VGPRs (128/thread) for all 512 steps.
// Per step: compute 32j x 8b slice (h read device-scope from group buffers),
// LDS cross-lane k-reduction, tanh+write slice, publish flag[block]=s+1
// (release), wait group flags >= s+1 (relaxed polls + one acquire fence).
// Monotonic flags: no reset. Double-buffered h: release path drains stores
// before flag publish, so +/-1-step skew is WAR-safe. Cooperative launch only
// for co-residency; correctness is placement-independent (agent-scope ops).
// ---------------------------------------------------------------------------
__global__ void __launch_bounds__(256, 1) persist2(
    float* __restrict__ ha, float* __restrict__ hb,
    const float* __restrict__ Whh, const float* __restrict__ P,
    const int* __restrict__ t, int* __restrict__ flags,
    const float* __restrict__ h0v) {
  __shared__ float4 part[64 * 64];    // [task][ks] 64 KB
  __shared__ int    t_lds[GB][SEQ];   // 16 KB
  __shared__ float4 P_lds[N_CHAR * 8];// [c][gq] 16 KB

  const int tid = threadIdx.x;
  const int jg = tid >> 6;            // wave id -> 8 j-rows
  const int ks = tid & 63;            // lane id -> 16 k's
  const int g = blockIdx.x >> 5;      // group
  const int m = blockIdx.x & 31;      // member
  const int b0 = g * GB;
  const int j0 = m * 32;

  // --- W_hh fragment (32 float4 = 128 VGPR), loaded once ---
  float4 w[2][4][4];
#pragma unroll
  for (int jql = 0; jql < 2; ++jql) {
#pragma unroll
    for (int jj = 0; jj < 4; ++jj) {
      const float4* wr = reinterpret_cast<const float4*>(
          Whh + (j0 + jg * 8 + jql * 4 + jj) * HIDDEN + (ks << 2));
      w[jql][jj][0] = wr[0];
      w[jql][jj][1] = wr[64];
      w[jql][jj][2] = wr[128];
      w[jql][jj][3] = wr[192];
    }
  }

  // --- preload t slice (8 rows) and P j-slice ---
#pragma unroll
  for (int i = 0; i < 4; ++i) {
    const int i4 = tid + 256 * i;
    const int row = i4 >> 7;
    const int col = (i4 & 127) * 4;
    *reinterpret_cast<int4*>(&t_lds[row][col]) =
        *reinterpret_cast<const int4*>(t + (b0 + row) * SEQ + col);
  }
#pragma unroll
  for (int i = 0; i < 4; ++i) {
    const int idx = tid + 256 * i;
    const int c = idx >> 3;
    const int gq = idx & 7;
    P_lds[idx] = *reinterpret_cast<const float4*>(P + c * HIDDEN + j0 + gq * 4);
  }
  __syncthreads();  // LDS preloads visible; ha init'd by initk (stream order)

  const float* cur = ha;
  float* nxt = hb;

  for (int s = 0; s < SEQ; ++s) {
    // --- wait for h_s from the other 31 members (skip s=0: initk made h_0) ---
    if (s > 0) {
      if (tid < 64) {
        const int base = g << 5;
        int v;
        do {
          v = (tid < 32 && tid != m)
                  ? __hip_atomic_load(&flags[base + tid], __ATOMIC_RELAXED,
                                      __HIP_MEMORY_SCOPE_AGENT)
                  : 0x7fffffff;
        } while (!__all(v >= s));
        __builtin_amdgcn_fence(__ATOMIC_ACQUIRE, "agent");
      }
      __syncthreads();
    }

    // --- compute: 8 bl x 8 j x 16 k = 1024 FMA/thread ---
    float4 acc[8][2];
#pragma unroll
    for (int bl = 0; bl < 8; ++bl) {
      const float4* hp =
          reinterpret_cast<const float4*>(cur + (b0 + bl) * HIDDEN + (ks << 2));
      float4 hq[4];
      hq[0] = hp[0];
      hq[1] = hp[64];
      hq[2] = hp[128];
      hq[3] = hp[192];
#pragma unroll
      for (int jql = 0; jql < 2; ++jql) {
        float4 a = make_float4(0.f, 0.f, 0.f, 0.f);
#pragma unroll
        for (int q = 0; q < 4; ++q) {
          a.x += dot4(w[jql][0][q], hq[q]);
          a.y += dot4(w[jql][1][q], hq[q]);
          a.z += dot4(w[jql][2][q], hq[q]);
          a.w += dot4(w[jql][3][q], hq[q]);
        }
        acc[bl][jql] = a;
      }
    }

    // --- partials to LDS ---
#pragma unroll
    for (int bl = 0; bl < 8; ++bl) {
#pragma unroll
      for (int jql = 0; jql < 2; ++jql)
        part[(bl * 8 + jg * 2 + jql) * 64 + ks] = acc[bl][jql];
    }
    __syncthreads();

    // --- finish: 64 tasks x 4 lanes; lane sums 16 partials + shfl ---
    {
      const int t4 = tid >> 2;
      const int q = tid & 3;
      const float4* p = &part[t4 * 64 + q * 16];
      float4 ssum = make_float4(0.f, 0.f, 0.f, 0.f);
#pragma unroll
      for (int i = 0; i < 16; ++i) {
        const float4 v = p[(i + tid) & 15];
        ssum.x += v.x; ssum.y += v.y; ssum.z += v.z; ssum.w += v.w;
      }
      ssum.x += __shfl_xor(ssum.x, 1); ssum.y += __shfl_xor(ssum.y, 1);
      ssum.z += __shfl_xor(ssum.z, 1); ssum.w += __shfl_xor(ssum.w, 1);
      ssum.x += __shfl_xor(ssum.x, 2); ssum.y += __shfl_xor(ssum.y, 2);
      ssum.z += __shfl_xor(ssum.z, 2); ssum.w += __shfl_xor(ssum.w, 2);
      if (q == 0) {
        const int bl = t4 >> 3;
        const int gq = t4 & 7;
        const int c = t_lds[bl][s];
        const float4 pq = P_lds[c * 8 + gq];
        float4 ho;
        ho.x = tanhf(pq.x + ssum.x);
        ho.y = tanhf(pq.y + ssum.y);
        ho.z = tanhf(pq.z + ssum.z);
        ho.w = tanhf(pq.w + ssum.w);
        *reinterpret_cast<float4*>(nxt + (b0 + bl) * HIDDEN + j0 + gq * 4) = ho;
      }
    }
    __syncthreads();  // all slice stores issued before publish

    // --- publish h_{s+1} ---
    if (tid == 0) {
      __builtin_amdgcn_fence(__ATOMIC_RELEASE, "agent");
      __hip_atomic_store(&flags[blockIdx.x], s + 1, __ATOMIC_RELAXED,
                         __HIP_MEMORY_SCOPE_AGENT);
    }

    const float* tmp = nxt; nxt = const_cast<float*>(cur); cur = tmp;
  }
}

// ---------------------------------------------------------------------------
// out[b][c] = sum_k h[b][k] * W_proj[c][k] + b_proj[c]
// ---------------------------------------------------------------------------
__global__ void outk(const float* __restrict__ h, const float* __restrict__ Wp,
                     const float* __restrict__ bp, float* __restrict__ out) {
  __shared__ float hbuf[HIDDEN];
  const int b = blockIdx.x;
  const int c = threadIdx.x;
  for (int i = threadIdx.x; i < HIDDEN / 4; i += blockDim.x) {
    reinterpret_cast<float4*>(hbuf)[i] =
        reinterpret_cast<const float4*>(h + b * HIDDEN)[i];
  }
  __syncthreads();
  const float4* w = reinterpret_cast<const float4*>(Wp + c * HIDDEN);
  float acc = 0.f;
#pragma unroll 8
  for (int k4 = 0; k4 < HIDDEN / 4; ++k4)
    acc += dot4(w[k4], reinterpret_cast<const float4*>(hbuf)[k4]);
  out[b * N_CHAR + c] = acc + bp[c];
}

// ---------------------------------------------------------------------------
extern "C" void kernel_launch(void* const* d_in, const int* in_sizes, int n_in,
                              void* d_out, int out_size, void* d_ws, size_t ws_size,
                              hipStream_t stream) {
  const int*   t   = (const int*)d_in[0];
  const float* emb = (const float*)d_in[1];
  const float* Wih = (const float*)d_in[2];
  const float* Whh = (const float*)d_in[3];
  const float* h0v = (const float*)d_in[4];
  const float* Wp  = (const float*)d_in[5];
  const float* bp  = (const float*)d_in[6];
  float* out = (float*)d_out;

  float* P  = (float*)d_ws;                 // 128*1024
  float* ha = P + N_CHAR * HIDDEN;          // 64*1024
  float* hb = ha + BATCH * HIDDEN;          // 64*1024
  int* flags = (int*)(hb + BATCH * HIDDEN); // 256 ints

  pk<<<512, 256, 0, stream>>>(emb, Wih, P);
  initk<<<256, 256, 0, stream>>>(h0v, ha, flags);

  {
    float* a0 = ha; float* a1 = hb;
    const float* a2 = Whh; const float* a3 = P;
    const int* a4 = t; int* a5 = flags; const float* a6 = h0v;
    void* kargs[] = {&a0, &a1, &a2, &a3, &a4, &a5, &a6};
    (void)hipLaunchCooperativeKernel((const void*)persist2, dim3(256),
                                     dim3(256), kargs, 0, stream);
  }

  // SEQ even -> final state in ha
  outk<<<BATCH, 128, 0, stream>>>(ha, Wp, bp, out);
}